// Round 2
// baseline (1258.102 us; speedup 1.0000x reference)
//
#include <hip/hip_runtime.h>
#include <hip/hip_bf16.h>

#define NIN 128
#define NH 64

// ---------------- CSR build ----------------

__global__ void k_count(const int* __restrict__ dst, int E, int* __restrict__ cnt) {
    int e = blockIdx.x * blockDim.x + threadIdx.x;
    int stride = gridDim.x * blockDim.x;
    for (; e < E; e += stride) atomicAdd(&cnt[dst[e]], 1);
}

// chunk = 1024 elements, block = 256 threads, 4 elems/thread
__global__ void k_chunksum(const int* __restrict__ cnt, int N, int* __restrict__ csum) {
    int t = threadIdx.x;
    int base = blockIdx.x * 1024 + t * 4;
    int s = 0;
#pragma unroll
    for (int j = 0; j < 4; j++) { int i = base + j; if (i < N) s += cnt[i]; }
    __shared__ int red[256];
    red[t] = s; __syncthreads();
    for (int w = 128; w > 0; w >>= 1) {
        if (t < w) red[t] += red[t + w];
        __syncthreads();
    }
    if (t == 0) csum[blockIdx.x] = red[0];
}

__global__ void k_chunkscan(const int* __restrict__ csum, int nchunks,
                            int* __restrict__ coff, int* __restrict__ row_ptr,
                            int N, int E) {
    __shared__ int buf[1024];
    int t = threadIdx.x;
    buf[t] = (t < nchunks) ? csum[t] : 0;
    __syncthreads();
    for (int ofs = 1; ofs < 1024; ofs <<= 1) {
        int v = (t >= ofs) ? buf[t - ofs] : 0;
        __syncthreads();
        buf[t] += v;
        __syncthreads();
    }
    if (t < nchunks) coff[t] = (t == 0) ? 0 : buf[t - 1];
    if (t == 0) row_ptr[N] = E;
}

__global__ void k_localscan(const int* __restrict__ cnt, int N, const int* __restrict__ coff,
                            int* __restrict__ row_ptr, int* __restrict__ cursor,
                            float* __restrict__ dis) {
    int t = threadIdx.x;
    int base = blockIdx.x * 1024 + t * 4;
    int c[4]; int s = 0;
#pragma unroll
    for (int j = 0; j < 4; j++) { int i = base + j; c[j] = (i < N) ? cnt[i] : 0; s += c[j]; }
    __shared__ int buf[256];
    buf[t] = s; __syncthreads();
    for (int ofs = 1; ofs < 256; ofs <<= 1) {
        int v = (t >= ofs) ? buf[t - ofs] : 0;
        __syncthreads();
        buf[t] += v;
        __syncthreads();
    }
    int run = coff[blockIdx.x] + ((t == 0) ? 0 : buf[t - 1]);
#pragma unroll
    for (int j = 0; j < 4; j++) {
        int i = base + j;
        if (i < N) {
            row_ptr[i] = run;
            cursor[i]  = run;
            dis[i]     = rsqrtf((float)(c[j] + 1));
            run += c[j];
        }
    }
}

__global__ void k_fill(const int* __restrict__ src, const int* __restrict__ dst, int E,
                       int* __restrict__ cursor, int* __restrict__ csr) {
    int e = blockIdx.x * blockDim.x + threadIdx.x;
    int stride = gridDim.x * blockDim.x;
    for (; e < E; e += stride) {
        int d = dst[e];
        int slot = atomicAdd(&cursor[d], 1);
        csr[slot] = src[e];
    }
}

// ---------------- dense GEMM: Hout[i][c] = dis[i] * sum_k X[i][k] W[k][c] ----------------
// block = 256 threads (4 waves), 32 nodes/block, 8 nodes/wave

template<int CIN>
__global__ __launch_bounds__(256) void k_gemm(const float* __restrict__ X,
                                              const float* __restrict__ W,
                                              const float* __restrict__ dis,
                                              float* __restrict__ Hout, int N) {
    __shared__ float Wl[CIN * 64];
    __shared__ float Xl[32 * CIN];
    int tid = threadIdx.x;

    const float4* W4 = (const float4*)W;
    float4* Wl4 = (float4*)Wl;
    for (int i = tid; i < CIN * 16; i += 256) Wl4[i] = W4[i];

    int node0 = blockIdx.x * 32;
    const float4* X4 = (const float4*)X + (size_t)node0 * (CIN / 4);
    float4* Xl4 = (float4*)Xl;
    long remain = (long)N * (CIN / 4) - (long)node0 * (CIN / 4);
    for (int i = tid; i < 8 * CIN; i += 256)
        Xl4[i] = (i < remain) ? X4[i] : make_float4(0.f, 0.f, 0.f, 0.f);
    __syncthreads();

    int lane = tid & 63, w = tid >> 6;
    float acc[8] = {0.f, 0.f, 0.f, 0.f, 0.f, 0.f, 0.f, 0.f};
    for (int k = 0; k < CIN; k += 4) {
        float w0 = Wl[(k + 0) * 64 + lane];
        float w1 = Wl[(k + 1) * 64 + lane];
        float w2 = Wl[(k + 2) * 64 + lane];
        float w3 = Wl[(k + 3) * 64 + lane];
#pragma unroll
        for (int j = 0; j < 8; j++) {
            float4 xv = *(const float4*)&Xl[(w * 8 + j) * CIN + k];
            acc[j] += xv.x * w0;
            acc[j] += xv.y * w1;
            acc[j] += xv.z * w2;
            acc[j] += xv.w * w3;
        }
    }
#pragma unroll
    for (int j = 0; j < 8; j++) {
        int n = node0 + w * 8 + j;
        if (n < N) Hout[(size_t)n * 64 + lane] = dis[n] * acc[j];
    }
}

// ---------------- aggregation: one wave per destination node ----------------
// acc = h'[d] + sum_{e in csr[d]} h'[src]; val = relu(dis[d]*acc + b)
// FINAL=false: store rows to Tout; FINAL=true: accumulate mean partials into gsum

template<bool FINAL>
__global__ __launch_bounds__(256) void k_agg(const float* __restrict__ H,
                                             const int* __restrict__ row_ptr,
                                             const int* __restrict__ csr,
                                             const float* __restrict__ dis,
                                             const float* __restrict__ bias,
                                             float* __restrict__ Tout,
                                             float* __restrict__ gsum, int N) {
    int wave = threadIdx.x >> 6, lane = threadIdx.x & 63;
    int d = blockIdx.x * 4 + wave;
    float val = 0.f;
    if (d < N) {
        float acc = H[(size_t)d * 64 + lane];  // self-loop contribution h'[d]
        int b0 = row_ptr[d], b1 = row_ptr[d + 1];
        for (int ofs = b0; ofs < b1; ofs += 64) {
            int rem = b1 - ofs;
            int m = rem < 64 ? rem : 64;
            int idx = (lane < m) ? csr[ofs + lane] : 0;
            int j = 0;
            for (; j + 4 <= m; j += 4) {
                int s0 = __shfl(idx, j, 64);
                int s1 = __shfl(idx, j + 1, 64);
                int s2 = __shfl(idx, j + 2, 64);
                int s3 = __shfl(idx, j + 3, 64);
                float v0 = H[(size_t)s0 * 64 + lane];
                float v1 = H[(size_t)s1 * 64 + lane];
                float v2 = H[(size_t)s2 * 64 + lane];
                float v3 = H[(size_t)s3 * 64 + lane];
                acc += v0; acc += v1; acc += v2; acc += v3;
            }
            for (; j < m; j++) {
                int s = __shfl(idx, j, 64);
                acc += H[(size_t)s * 64 + lane];
            }
        }
        val = fmaxf(dis[d] * acc + bias[lane], 0.f);
        if (!FINAL) Tout[(size_t)d * 64 + lane] = val;
    }
    if (FINAL) {
        __shared__ float red[4][64];
        red[wave][lane] = val;
        __syncthreads();
        if (wave == 0) {
            float s = red[0][lane] + red[1][lane] + red[2][lane] + red[3][lane];
            atomicAdd(&gsum[lane], s);
        }
    }
}

__global__ void k_final(const float* __restrict__ gsum, const float* __restrict__ fcW,
                        const float* __restrict__ fcb, float* __restrict__ out, float invN) {
    int j = threadIdx.x;
    if (j < 2) {
        float s = 0.f;
        for (int c = 0; c < 64; c++) s += gsum[c] * invN * fcW[c * 2 + j];
        out[j] = s + fcb[j];
    }
}

extern "C" void kernel_launch(void* const* d_in, const int* in_sizes, int n_in,
                              void* d_out, int out_size, void* d_ws, size_t ws_size,
                              hipStream_t stream) {
    const float* x   = (const float*)d_in[0];
    const int*   ei  = (const int*)d_in[1];
    const float* W1  = (const float*)d_in[2];
    const float* b1  = (const float*)d_in[3];
    const float* W2  = (const float*)d_in[4];
    const float* b2  = (const float*)d_in[5];
    const float* fcW = (const float*)d_in[6];
    const float* fcb = (const float*)d_in[7];

    int N = in_sizes[0] / NIN;
    int E = in_sizes[1] / 2;
    const int* src = ei;
    const int* dst = ei + E;

    char* ws = (char*)d_ws;
    size_t off = 0;
    auto take = [&](size_t bytes) -> char* {
        char* p = ws + off;
        off = (off + bytes + 255) & ~(size_t)255;
        return p;
    };
    float* dis     = (float*)take((size_t)N * 4);
    int*   cnt     = (int*)take((size_t)N * 4);
    int*   row_ptr = (int*)take((size_t)(N + 1) * 4);
    int*   cursor  = (int*)take((size_t)N * 4);
    int*   csum    = (int*)take(1024 * 4);
    int*   coff    = (int*)take(1024 * 4);
    int*   csr     = (int*)take((size_t)E * 4);
    float* hbuf    = (float*)take((size_t)N * 64 * 4);
    float* tbuf    = (float*)take((size_t)N * 64 * 4);
    float* gsum    = (float*)take(64 * 4);

    hipMemsetAsync(cnt, 0, (size_t)N * 4, stream);
    hipMemsetAsync(gsum, 0, 64 * 4, stream);

    int nchunks = (N + 1023) / 1024;
    k_count<<<2048, 256, 0, stream>>>(dst, E, cnt);
    k_chunksum<<<nchunks, 256, 0, stream>>>(cnt, N, csum);
    k_chunkscan<<<1, 1024, 0, stream>>>(csum, nchunks, coff, row_ptr, N, E);
    k_localscan<<<nchunks, 256, 0, stream>>>(cnt, N, coff, row_ptr, cursor, dis);
    k_fill<<<2048, 256, 0, stream>>>(src, dst, E, cursor, csr);

    k_gemm<NIN><<<(N + 31) / 32, 256, 0, stream>>>(x, W1, dis, hbuf, N);
    k_agg<false><<<(N + 3) / 4, 256, 0, stream>>>(hbuf, row_ptr, csr, dis, b1, tbuf, nullptr, N);
    k_gemm<NH><<<(N + 31) / 32, 256, 0, stream>>>(tbuf, W2, dis, hbuf, N);
    k_agg<true><<<(N + 3) / 4, 256, 0, stream>>>(hbuf, row_ptr, csr, dis, b2, nullptr, gsum, N);
    k_final<<<1, 64, 0, stream>>>(gsum, fcW, fcb, (float*)d_out, 1.0f / (float)N);
}

// Round 5
// 1207.216 us; speedup vs baseline: 1.0422x; 1.0422x over previous
//
#include <hip/hip_runtime.h>
#include <hip/hip_bf16.h>

#define NIN 128
#define NH 64

// ---------------- CSR build ----------------

__global__ void k_count(const int* __restrict__ dst, int E, int* __restrict__ cnt) {
    int e = blockIdx.x * blockDim.x + threadIdx.x;
    int stride = gridDim.x * blockDim.x;
    for (; e < E; e += stride) atomicAdd(&cnt[dst[e]], 1);
}

// chunk = 1024 elements, block = 256 threads, 4 elems/thread
__global__ void k_chunksum(const int* __restrict__ cnt, int N, int* __restrict__ csum) {
    int t = threadIdx.x;
    int base = blockIdx.x * 1024 + t * 4;
    int s = 0;
#pragma unroll
    for (int j = 0; j < 4; j++) { int i = base + j; if (i < N) s += cnt[i]; }
    __shared__ int red[256];
    red[t] = s; __syncthreads();
    for (int w = 128; w > 0; w >>= 1) {
        if (t < w) red[t] += red[t + w];
        __syncthreads();
    }
    if (t == 0) csum[blockIdx.x] = red[0];
}

__global__ void k_chunkscan(const int* __restrict__ csum, int nchunks,
                            int* __restrict__ coff, int* __restrict__ row_ptr,
                            int N, int E) {
    __shared__ int buf[1024];
    int t = threadIdx.x;
    buf[t] = (t < nchunks) ? csum[t] : 0;
    __syncthreads();
    for (int ofs = 1; ofs < 1024; ofs <<= 1) {
        int v = (t >= ofs) ? buf[t - ofs] : 0;
        __syncthreads();
        buf[t] += v;
        __syncthreads();
    }
    if (t < nchunks) coff[t] = (t == 0) ? 0 : buf[t - 1];
    if (t == 0) row_ptr[N] = E;
}

__global__ void k_localscan(const int* __restrict__ cnt, int N, const int* __restrict__ coff,
                            int* __restrict__ row_ptr, int* __restrict__ cursor,
                            float* __restrict__ dis) {
    int t = threadIdx.x;
    int base = blockIdx.x * 1024 + t * 4;
    int c[4]; int s = 0;
#pragma unroll
    for (int j = 0; j < 4; j++) { int i = base + j; c[j] = (i < N) ? cnt[i] : 0; s += c[j]; }
    __shared__ int buf[256];
    buf[t] = s; __syncthreads();
    for (int ofs = 1; ofs < 256; ofs <<= 1) {
        int v = (t >= ofs) ? buf[t - ofs] : 0;
        __syncthreads();
        buf[t] += v;
        __syncthreads();
    }
    int run = coff[blockIdx.x] + ((t == 0) ? 0 : buf[t - 1]);
#pragma unroll
    for (int j = 0; j < 4; j++) {
        int i = base + j;
        if (i < N) {
            row_ptr[i] = run;
            cursor[i]  = run;
            dis[i]     = rsqrtf((float)(c[j] + 1));
            run += c[j];
        }
    }
}

__global__ void k_fill(const int* __restrict__ src, const int* __restrict__ dst, int E,
                       int* __restrict__ cursor, int* __restrict__ csr) {
    int e = blockIdx.x * blockDim.x + threadIdx.x;
    int stride = gridDim.x * blockDim.x;
    for (; e < E; e += stride) {
        int d = dst[e];
        int slot = atomicAdd(&cursor[d], 1);
        csr[slot] = src[e];
    }
}

// ---------------- dense GEMM: Hb[i][c] = bf16(dis[i] * sum_k X[i][k] W[k][c]) ----------------
// block = 256 threads (4 waves), 32 nodes/block, 8 nodes/wave

template<int CIN>
__global__ __launch_bounds__(256) void k_gemm(const float* __restrict__ X,
                                              const float* __restrict__ W,
                                              const float* __restrict__ dis,
                                              __hip_bfloat16* __restrict__ Hb, int N) {
    __shared__ float Wl[CIN * 64];
    __shared__ float Xl[32 * CIN];
    int tid = threadIdx.x;

    const float4* W4 = (const float4*)W;
    float4* Wl4 = (float4*)Wl;
    for (int i = tid; i < CIN * 16; i += 256) Wl4[i] = W4[i];

    int node0 = blockIdx.x * 32;
    const float4* X4 = (const float4*)X + (size_t)node0 * (CIN / 4);
    float4* Xl4 = (float4*)Xl;
    long remain = (long)N * (CIN / 4) - (long)node0 * (CIN / 4);
    for (int i = tid; i < 8 * CIN; i += 256)
        Xl4[i] = (i < remain) ? X4[i] : make_float4(0.f, 0.f, 0.f, 0.f);
    __syncthreads();

    int lane = tid & 63, w = tid >> 6;
    float acc[8] = {0.f, 0.f, 0.f, 0.f, 0.f, 0.f, 0.f, 0.f};
    for (int k = 0; k < CIN; k += 4) {
        float w0 = Wl[(k + 0) * 64 + lane];
        float w1 = Wl[(k + 1) * 64 + lane];
        float w2 = Wl[(k + 2) * 64 + lane];
        float w3 = Wl[(k + 3) * 64 + lane];
#pragma unroll
        for (int j = 0; j < 8; j++) {
            float4 xv = *(const float4*)&Xl[(w * 8 + j) * CIN + k];
            acc[j] += xv.x * w0;
            acc[j] += xv.y * w1;
            acc[j] += xv.z * w2;
            acc[j] += xv.w * w3;
        }
    }
#pragma unroll
    for (int j = 0; j < 8; j++) {
        int n = node0 + w * 8 + j;
        if (n < N) Hb[(size_t)n * 64 + lane] = __float2bfloat16(dis[n] * acc[j]);
    }
}

// ---------------- aggregation: one wave per destination node, bf16 rows ----------------
// Row = 64 bf16 = 128 B = one cache line. Lane (quad = lane>>4, hw = lane&15):
// one uint2 wave-load fetches 4 edge rows; 8 groups unrolled = 32 edges in flight.
// acc f32; quad partials folded via shfl_xor(16/32); self row prefetched; pad row N = zeros.

#define ACC4(e) { a0 += __uint_as_float((e).x << 16); a1 += __uint_as_float((e).x & 0xffff0000u); \
                  a2 += __uint_as_float((e).y << 16); a3 += __uint_as_float((e).y & 0xffff0000u); }

template<bool FINAL>
__global__ __launch_bounds__(256) void k_agg(const uint2* __restrict__ H2,
                                             const int* __restrict__ row_ptr,
                                             const int* __restrict__ csr,
                                             const float* __restrict__ dis,
                                             const float* __restrict__ bias,
                                             float4* __restrict__ Tout,
                                             float* __restrict__ gsum, int N) {
    int wave = threadIdx.x >> 6, lane = threadIdx.x & 63;
    int quad = lane >> 4;   // row within a 4-row group
    int hw   = lane & 15;   // 8B slot within the 128B row
    int d = blockIdx.x * 4 + wave;
    float v0 = 0.f, v1 = 0.f, v2 = 0.f, v3 = 0.f;
    if (d < N) {
        uint2 sv = H2[(size_t)d * 16 + hw];  // self row, prefetched
        float a0 = 0.f, a1 = 0.f, a2 = 0.f, a3 = 0.f;
        int b0 = row_ptr[d], b1 = row_ptr[d + 1];
        for (int ofs = b0; ofs < b1; ofs += 32) {
            int m = b1 - ofs; m = m < 32 ? m : 32;
            int idx = (lane < m) ? csr[ofs + lane] : N;  // pad -> zero row
            int r0 = __shfl(idx,  0 + quad, 64);
            int r1 = __shfl(idx,  4 + quad, 64);
            int r2 = __shfl(idx,  8 + quad, 64);
            int r3 = __shfl(idx, 12 + quad, 64);
            int r4 = __shfl(idx, 16 + quad, 64);
            int r5 = __shfl(idx, 20 + quad, 64);
            int r6 = __shfl(idx, 24 + quad, 64);
            int r7 = __shfl(idx, 28 + quad, 64);
            uint2 e0 = H2[(size_t)r0 * 16 + hw];
            uint2 e1 = H2[(size_t)r1 * 16 + hw];
            uint2 e2 = H2[(size_t)r2 * 16 + hw];
            uint2 e3 = H2[(size_t)r3 * 16 + hw];
            uint2 e4 = H2[(size_t)r4 * 16 + hw];
            uint2 e5 = H2[(size_t)r5 * 16 + hw];
            uint2 e6 = H2[(size_t)r6 * 16 + hw];
            uint2 e7 = H2[(size_t)r7 * 16 + hw];
            ACC4(e0); ACC4(e1); ACC4(e2); ACC4(e3);
            ACC4(e4); ACC4(e5); ACC4(e6); ACC4(e7);
        }
        // fold the 4 quads (each holds a disjoint edge subset)
        a0 += __shfl_xor(a0, 16, 64); a0 += __shfl_xor(a0, 32, 64);
        a1 += __shfl_xor(a1, 16, 64); a1 += __shfl_xor(a1, 32, 64);
        a2 += __shfl_xor(a2, 16, 64); a2 += __shfl_xor(a2, 32, 64);
        a3 += __shfl_xor(a3, 16, 64); a3 += __shfl_xor(a3, 32, 64);
        // self-loop contribution
        a0 += __uint_as_float(sv.x << 16);
        a1 += __uint_as_float(sv.x & 0xffff0000u);
        a2 += __uint_as_float(sv.y << 16);
        a3 += __uint_as_float(sv.y & 0xffff0000u);
        float dd = dis[d];
        float4 bv = ((const float4*)bias)[hw];
        v0 = fmaxf(fmaf(dd, a0, bv.x), 0.f);
        v1 = fmaxf(fmaf(dd, a1, bv.y), 0.f);
        v2 = fmaxf(fmaf(dd, a2, bv.z), 0.f);
        v3 = fmaxf(fmaf(dd, a3, bv.w), 0.f);
        if (!FINAL && lane < 16) Tout[(size_t)d * 16 + hw] = make_float4(v0, v1, v2, v3);
    }
    if (FINAL) {
        __shared__ float4 red4[4][16];
        if (lane < 16) red4[wave][hw] = make_float4(v0, v1, v2, v3);
        __syncthreads();
        if (wave == 0) {
            const float* rf = (const float*)red4;
            float s = rf[lane] + rf[64 + lane] + rf[128 + lane] + rf[192 + lane];
            atomicAdd(&gsum[lane], s);
        }
    }
}

__global__ void k_final(const float* __restrict__ gsum, const float* __restrict__ fcW,
                        const float* __restrict__ fcb, float* __restrict__ out, float invN) {
    int j = threadIdx.x;
    if (j < 2) {
        float s = 0.f;
        for (int c = 0; c < 64; c++) s += gsum[c] * invN * fcW[c * 2 + j];
        out[j] = s + fcb[j];
    }
}

extern "C" void kernel_launch(void* const* d_in, const int* in_sizes, int n_in,
                              void* d_out, int out_size, void* d_ws, size_t ws_size,
                              hipStream_t stream) {
    const float* x   = (const float*)d_in[0];
    const int*   ei  = (const int*)d_in[1];
    const float* W1  = (const float*)d_in[2];
    const float* b1  = (const float*)d_in[3];
    const float* W2  = (const float*)d_in[4];
    const float* b2  = (const float*)d_in[5];
    const float* fcW = (const float*)d_in[6];
    const float* fcb = (const float*)d_in[7];

    int N = in_sizes[0] / NIN;
    int E = in_sizes[1] / 2;
    const int* src = ei;
    const int* dst = ei + E;

    char* ws = (char*)d_ws;
    size_t off = 0;
    auto take = [&](size_t bytes) -> char* {
        char* p = ws + off;
        off = (off + bytes + 255) & ~(size_t)255;
        return p;
    };
    float* dis     = (float*)take((size_t)N * 4);
    int*   cnt     = (int*)take((size_t)N * 4);
    int*   row_ptr = (int*)take((size_t)(N + 1) * 4);
    int*   cursor  = (int*)take((size_t)N * 4);
    int*   csum    = (int*)take(1024 * 4);
    int*   coff    = (int*)take(1024 * 4);
    int*   csr     = (int*)take((size_t)E * 4);
    char*  hbuf    = take((size_t)(N + 1) * 64 * 2);  // bf16 rows, +1 zero pad row
    float* tbuf    = (float*)take((size_t)N * 64 * 4);
    float* gsum    = (float*)take(64 * 4);

    hipMemsetAsync(cnt, 0, (size_t)N * 4, stream);
    hipMemsetAsync(gsum, 0, 64 * 4, stream);
    hipMemsetAsync(hbuf + (size_t)N * 128, 0, 128, stream);  // zero pad row

    int nchunks = (N + 1023) / 1024;
    k_count<<<2048, 256, 0, stream>>>(dst, E, cnt);
    k_chunksum<<<nchunks, 256, 0, stream>>>(cnt, N, csum);
    k_chunkscan<<<1, 1024, 0, stream>>>(csum, nchunks, coff, row_ptr, N, E);
    k_localscan<<<nchunks, 256, 0, stream>>>(cnt, N, coff, row_ptr, cursor, dis);
    k_fill<<<2048, 256, 0, stream>>>(src, dst, E, cursor, csr);

    k_gemm<NIN><<<(N + 31) / 32, 256, 0, stream>>>(x, W1, dis, (__hip_bfloat16*)hbuf, N);
    k_agg<false><<<(N + 3) / 4, 256, 0, stream>>>((const uint2*)hbuf, row_ptr, csr, dis, b1,
                                                  (float4*)tbuf, nullptr, N);
    k_gemm<NH><<<(N + 31) / 32, 256, 0, stream>>>(tbuf, W2, dis, (__hip_bfloat16*)hbuf, N);
    k_agg<true><<<(N + 3) / 4, 256, 0, stream>>>((const uint2*)hbuf, row_ptr, csr, dis, b2,
                                                 nullptr, gsum, N);
    k_final<<<1, 64, 0, stream>>>(gsum, fcW, fcb, (float*)d_out, 1.0f / (float)N);
}